// Round 4
// baseline (504.950 us; speedup 1.0000x reference)
//
#include <hip/hip_runtime.h>
#include <math.h>

#define TOKS  16384
#define HD    4096
#define NE    64
#define MT    16          // tokens per block (one MFMA M-tile)
#define KT    64          // K per tile iteration
#define NTHR  256         // 4 waves; each wave: 16 tokens x 16 experts
#define NTILE (HD / KT)   // 64

typedef unsigned int   u32;
typedef unsigned short u16;
typedef short v8s __attribute__((ext_vector_type(8)));   // 8 bf16
typedef float v4f __attribute__((ext_vector_type(4)));   // 4 fp32

// exact-ish split: a ≈ hi + lo, both bf16 truncations; packs (a,b) -> one u32 each
__device__ __forceinline__ void split2(float a, float b, u32& hi, u32& lo) {
    u32 ua = __float_as_uint(a), ub = __float_as_uint(b);
    hi = (ub & 0xffff0000u) | (ua >> 16);
    float la = a - __uint_as_float(ua & 0xffff0000u);
    float lb = b - __uint_as_float(ub & 0xffff0000u);
    lo = (__float_as_uint(lb) & 0xffff0000u) | (__float_as_uint(la) >> 16);
}

// Pre-pass: split W [NE][HD] fp32 -> bf16 hi/lo planes in d_ws (row-major u16)
__global__ __launch_bounds__(256) void wsplit_kernel(const float* __restrict__ W,
                                                     u16* __restrict__ wh, u16* __restrict__ wl) {
    const int gid = blockIdx.x * 256 + threadIdx.x;   // 65536 threads, one float4 each
    const float4 f = ((const float4*)W)[gid];
    u32 h0, h1, l0, l1;
    split2(f.x, f.y, h0, l0);
    split2(f.z, f.w, h1, l1);
    u32* whp = (u32*)wh; u32* wlp = (u32*)wl;
    whp[gid * 2 + 0] = h0; whp[gid * 2 + 1] = h1;
    wlp[gid * 2 + 0] = l0; wlp[gid * 2 + 1] = l1;
}

union U4S8 { uint4 u; v8s s; };

__global__ __launch_bounds__(NTHR, 4) void router_kernel(
    const float* __restrict__ x, const u16* __restrict__ wh, const u16* __restrict__ wl,
    float* __restrict__ scores, float* __restrict__ wout, float* __restrict__ iout)
{
    __shared__ float Ls[MT][NE + 1];
    __shared__ float Ssum[MT], Smax[MT];

    const int t    = threadIdx.x;
    const int tok0 = blockIdx.x * MT;
    const int lane = t & 63;
    const int w    = t >> 6;          // wave id 0..3 -> expert group
    const int q    = lane >> 4;       // k-chunk selector (A & B frag layout)
    const int r    = lane & 15;       // row within tile (token for A, expert for B)

    const size_t xrow = (size_t)(tok0 + r) * HD;        // A: token row, fp32
    const size_t wrow = (size_t)(w * 16 + r) * HD;      // B: expert row, bf16 planes
    const int q8 = q * 8;

    v4f acc = {0.f, 0.f, 0.f, 0.f};

    // ping-pong register sets; no LDS, no barriers in the K-loop
    float4 ax[2][4];   // fp32 x chunks: [c*2 + half]
    uint4  bw[2][4];   // [0]=bh c0, [1]=bh c1, [2]=bl c0, [3]=bl c1

#define LOADT(S, K0)                                                   \
    do {                                                               \
        ax[S][0] = *(const float4*)&x[xrow + (K0) + q8];               \
        ax[S][1] = *(const float4*)&x[xrow + (K0) + q8 + 4];           \
        ax[S][2] = *(const float4*)&x[xrow + (K0) + 32 + q8];          \
        ax[S][3] = *(const float4*)&x[xrow + (K0) + 32 + q8 + 4];      \
        bw[S][0] = *(const uint4*)&wh[wrow + (K0) + q8];               \
        bw[S][1] = *(const uint4*)&wh[wrow + (K0) + 32 + q8];          \
        bw[S][2] = *(const uint4*)&wl[wrow + (K0) + q8];               \
        bw[S][3] = *(const uint4*)&wl[wrow + (K0) + 32 + q8];          \
    } while (0)

#define COMPUTE(S)                                                     \
    do {                                                               \
        _Pragma("unroll")                                              \
        for (int c = 0; c < 2; ++c) {                                  \
            const float4 p = ax[S][2 * c], s2 = ax[S][2 * c + 1];      \
            u32 h0, l0, h1, l1, h2, l2, h3, l3;                        \
            split2(p.x, p.y, h0, l0);  split2(p.z, p.w, h1, l1);       \
            split2(s2.x, s2.y, h2, l2); split2(s2.z, s2.w, h3, l3);    \
            U4S8 ah, al, bh, bl;                                       \
            ah.u = make_uint4(h0, h1, h2, h3);                         \
            al.u = make_uint4(l0, l1, l2, l3);                         \
            bh.u = bw[S][c];                                           \
            bl.u = bw[S][2 + c];                                       \
            acc = __builtin_amdgcn_mfma_f32_16x16x32_bf16(ah.s, bh.s, acc, 0, 0, 0); \
            acc = __builtin_amdgcn_mfma_f32_16x16x32_bf16(al.s, bh.s, acc, 0, 0, 0); \
            acc = __builtin_amdgcn_mfma_f32_16x16x32_bf16(ah.s, bl.s, acc, 0, 0, 0); \
        }                                                              \
    } while (0)

    LOADT(0, 0);
#pragma unroll 2
    for (int tile = 0; tile < NTILE; ++tile) {
        const int buf = tile & 1;
        if (tile + 1 < NTILE) LOADT(buf ^ 1, (tile + 1) * KT);
        COMPUTE(buf);
    }
#undef LOADT
#undef COMPUTE

    // scatter logits to LDS: D layout row(token) = q*4+reg, col(expert) = lane&15
#pragma unroll
    for (int reg = 0; reg < 4; ++reg)
        Ls[q * 4 + reg][w * 16 + r] = acc[reg];
    __syncthreads();

    // per-token softmax + top-2 (verified rounds 1-3)
    if (t < MT) {
        const int tk = t;
        float m = -3.402823466e+38f;
        for (int e = 0; e < NE; ++e) m = fmaxf(m, Ls[tk][e]);
        float s = 0.f;
        float v1 = -1.f, v2 = -1.f;
        int   i1 = 0, i2 = 0;
        for (int e = 0; e < NE; ++e) {
            const float ex = expf(Ls[tk][e] - m);
            s += ex;
            if (ex > v1)      { v2 = v1; i2 = i1; v1 = ex; i1 = e; }
            else if (ex > v2) { v2 = ex; i2 = e; }
        }
        const float s1 = v1 / s, s2 = v2 / s;
        const float ws_ = s1 + s2;
        wout[(size_t)(tok0 + tk) * 2 + 0] = s1 / ws_;
        wout[(size_t)(tok0 + tk) * 2 + 1] = s2 / ws_;
        iout[(size_t)(tok0 + tk) * 2 + 0] = (float)i1;
        iout[(size_t)(tok0 + tk) * 2 + 1] = (float)i2;
        Ssum[tk] = s;
        Smax[tk] = m;
    }
    __syncthreads();

    // coalesced scores write: 16*64 = 1024 elems / 256 threads
#pragma unroll
    for (int it = 0; it < (MT * NE) / NTHR; ++it) {
        const int f  = it * NTHR + t;
        const int tk = f >> 6, e = f & 63;
        scores[(size_t)(tok0 + tk) * NE + e] = expf(Ls[tk][e] - Smax[tk]) / Ssum[tk];
    }
}

extern "C" void kernel_launch(void* const* d_in, const int* in_sizes, int n_in,
                              void* d_out, int out_size, void* d_ws, size_t ws_size,
                              hipStream_t stream) {
    (void)in_sizes; (void)n_in; (void)out_size; (void)ws_size;
    const float* x = (const float*)d_in[0];
    const float* W = (const float*)d_in[1];
    float* out    = (float*)d_out;
    float* scores = out;
    float* wout   = scores + (size_t)TOKS * NE;
    float* iout   = wout   + (size_t)TOKS * 2;

    u16* wh = (u16*)d_ws;
    u16* wl = wh + (size_t)NE * HD;

    wsplit_kernel<<<dim3(256), dim3(256), 0, stream>>>(W, wh, wl);
    router_kernel<<<dim3(TOKS / MT), dim3(NTHR), 0, stream>>>(x, wh, wl, scores, wout, iout);
}